// Round 15
// baseline (121.111 us; speedup 1.0000x reference)
//
#include <hip/hip_runtime.h>

// RK4 Gray-Scott, y-march, STATIC circular register windows, packed-f32.
// Horizontal +-3 neighbor exchange now via DPP cross-lane (VALU pipe):
// the consumer's lag-3 window register IS the row; row_shr:1/2 / row_shl:1/2
// deliver lane l-1,l-2 / l+1,l+2 values. 16-lane-row boundary lanes
// ((tid&15)<2 or >=14) fall back to the f4-packed LDS row (same 4-slot,
// barrier-every-2-steps protocol as before; writes unchanged).
// Per stage per channel: 6 DPP movs (only used pieces: m1.xy, m2.y, p1.xy,
// p2.x) instead of 4 full ds_read_b128. LDS pipe ~1920 -> ~1050 cyc/CU-step.
// RK fold: AC = 4*Y1 + 8*Y2 - 4*u0 (row yL-6); out = (AC[lag6]+4*Y3c+k4)/12.

typedef float f2 __attribute__((ext_vector_type(2)));
typedef float f4 __attribute__((ext_vector_type(4)));

#define HROWS 64
#define NT    512
#define STEPS (HROWS + 24)   // 88

#define W0 ((-980.0f / 1e-4f) / 180.0f)
#define W1 ((  270.0f / 1e-4f) / 180.0f)
#define W2 (( -27.0f / 1e-4f) / 180.0f)
#define W3 ((   2.0f / 1e-4f) / 180.0f)

// DPP controls: row_shr:N => lane i reads lane i-N (invalid (i&15)<N);
//               row_shl:N => lane i reads lane i+N (invalid (i&15)>=16-N).
#define DPP_M1 0x111
#define DPP_M2 0x112
#define DPP_P1 0x101
#define DPP_P2 0x102

__device__ __forceinline__ f2 sp(float s) { f2 r; r.x = s; r.y = s; return r; }
__device__ __forceinline__ f2 pfma(float s, f2 a, f2 c) {
    return __builtin_elementwise_fma(sp(s), a, c);
}
__device__ __forceinline__ f2 lo2(f4 a) { return __builtin_shufflevector(a, a, 0, 1); }
__device__ __forceinline__ f2 hi2(f4 a) { return __builtin_shufflevector(a, a, 2, 3); }
__device__ __forceinline__ f4 cat(f2 a, f2 b) { return __builtin_shufflevector(a, b, 0, 1, 2, 3); }

template<int C>
__device__ __forceinline__ float dppf(float x) {
    return __int_as_float(__builtin_amdgcn_update_dpp(
        0, __float_as_int(x), C, 0xF, 0xF, false));
}
template<int C>
__device__ __forceinline__ f2 dpp2(f2 x) {
    f2 r; r.x = dppf<C>(x.x); r.y = dppf<C>(x.y); return r;
}

// 13-pt Laplacian, packed over 2 cols (a=2l, b=2l+1).
// w0..w6 = vertical rows lag6..lag0 (center w3). m1 = lane l-1 f2, p1 = lane
// l+1 f2, am3 = col a-3 (lane l-2 .y), bp3 = col b+3 (lane l+2 .x).
__device__ __forceinline__ void evalp7(f2 w0, f2 w1, f2 w2, f2 w3, f2 w4,
                                       f2 w5, f2 w6, f2 m1, f2 p1,
                                       float am3, float bp3,
                                       f2& lap, f2& ctr)
{
    ctr = w3;
    f2 vp = pfma(W1, w2 + w4, pfma(W2, w1 + w5, sp(W3) * (w0 + w6)));
    f2 m1q; m1q.x = m1.y;  m1q.y = ctr.x;   // {a-1, b-1}
    f2 p1q; p1q.x = ctr.y; p1q.y = p1.x;    // {a+1, b+1}
    f2 m3q; m3q.x = am3;   m3q.y = m1.x;    // {a-3, b-3}
    f2 p3q; p3q.x = p1.y;  p3q.y = bp3;     // {a+3, b+3}
    f2 hp = pfma(W1, m1q + p1q, pfma(W2, m1 + p1, sp(W3) * (m3q + p3q)));
    lap = pfma(W0, ctr, hp + vp);
}

__global__ __launch_bounds__(NT, 1) void rcnn_rk4_march(
    const float* __restrict__ h,
    const float* __restrict__ pCA, const float* __restrict__ pCB,
    const float* __restrict__ pNA, const float* __restrict__ pNB,
    const float* __restrict__ pf,  const float* __restrict__ pk,
    float* __restrict__ out)
{
    __shared__ f4 S[4][4][NT];   // [stage][slot][col] = 128 KiB

    const int tid = threadIdx.x;
    const int Y0  = blockIdx.x * HROWS;
    const int b   = blockIdx.z;

    const float NA = pNA[0], NB = pNB[0];
    const float ff = pf[0];
    const float kpf = pk[0] + pf[0];
    const float mu_u = 4e-5f / (1.0f + expf(-pCA[0]));
    const float mu_v = 4e-5f / (1.0f + expf(-pCB[0]));

    const size_t baseU = (size_t)b * 2u * 1048576u;
    const size_t baseV = baseU + 1048576u;
    const float* hU = h + baseU + 2 * tid;
    const float* hV = h + baseV + 2 * tid;
    float* oU = out + baseU + 2 * tid;
    float* oV = out + baseV + 2 * tid;

    const int xm2 = (tid - 2) & 511;
    const int xm1 = (tid - 1) & 511;
    const int xp1 = (tid + 1) & 511;
    const int xp2 = (tid + 2) & 511;
    const int l16 = tid & 15;

    f2 Uu[8], Uv[8], Du[8], Dv[8];
    f2 Y1u[8], Y1v[8], Y2u[8], Y2v[8], Y3u[8], Y3v[8];
    f2 ACu[8], ACv[8];

    const f2 z = sp(0.0f);
    #pragma unroll
    for (int j = 0; j < 8; ++j) {
        Uu[j]=z; Uv[j]=z; Du[j]=z; Dv[j]=z;
        Y1u[j]=z; Y1v[j]=z; Y2u[j]=z; Y2v[j]=z; Y3u[j]=z; Y3v[j]=z;
        ACu[j]=z; ACv[j]=z;
    }

    // 2-deep prefetch: pA = even steps, pB = odd steps
    f2 pAu, pAv, pBu, pBv;
    {
        int r0 = (Y0 - 12) & 1023;
        int r1 = (Y0 - 11) & 1023;
        pAu = *(const f2*)(hU + (size_t)r0 * 1024);
        pAv = *(const f2*)(hV + (size_t)r0 * 1024);
        pBu = *(const f2*)(hU + (size_t)r1 * 1024);
        pBv = *(const f2*)(hV + (size_t)r1 * 1024);
    }

// Neighbor block: DPP for interior, LDS (slot (c+2)&3, written at t-2) for
// 16-lane-row boundary lanes.
#define NBR(Warr_u, Warr_v, sidx, cc)                                         \
      f2 w3u = Warr_u[((cc)+5)&7], w3v = Warr_v[((cc)+5)&7];                  \
      f2 m1u = dpp2<DPP_M1>(w3u), p1u = dpp2<DPP_P1>(w3u);                    \
      f2 m1v = dpp2<DPP_M1>(w3v), p1v = dpp2<DPP_P1>(w3v);                    \
      float am3u = dppf<DPP_M2>(w3u.y), am3v = dppf<DPP_M2>(w3v.y);           \
      float bp3u = dppf<DPP_P2>(w3u.x), bp3v = dppf<DPP_P2>(w3v.x);           \
      {                                                                       \
        const f4* Ls = &S[sidx][((cc)+2)&3][0];                               \
        if (l16 < 2) {                                                        \
          f4 t1 = Ls[xm1], t2 = Ls[xm2];                                      \
          m1u = lo2(t1); m1v = hi2(t1);                                       \
          am3u = lo2(t2).y; am3v = hi2(t2).y;                                 \
        }                                                                     \
        if (l16 >= 14) {                                                      \
          f4 t1 = Ls[xp1], t2 = Ls[xp2];                                      \
          p1u = lo2(t1); p1v = hi2(t1);                                       \
          bp3u = lo2(t2).x; bp3v = hi2(t2).x;                                 \
        }                                                                     \
      }

#define STEP(c, G1, G2, G3, G4, tb_)                                          \
  {                                                                           \
    const int t_ = (tb_) + (c);                                               \
    /* delay copy: D[c] = u0 lag 5 (phase (c+3)&7) */                         \
    Du[(c)&7] = Uu[((c)+3)&7]; Dv[(c)&7] = Uv[((c)+3)&7];                     \
    /* consume prefetch: u0 row yL */                                         \
    Uu[(c)&7] = ((c)&1) ? pBu : pAu;                                          \
    Uv[(c)&7] = ((c)&1) ? pBv : pAv;                                          \
    /* u0 row yL-1 (lag 1, phase (c+7)&7) -> slot c&3 */                      \
    S[0][(c)&3][tid] = cat(Uu[((c)+7)&7], Uv[((c)+7)&7]);                     \
    /* issue prefetch for row yL+2 */                                         \
    {                                                                         \
      int yn = (Y0 - 10 + t_) & 1023;                                         \
      f2 au = *(const f2*)(hU + (size_t)yn * 1024);                           \
      f2 av = *(const f2*)(hV + (size_t)yn * 1024);                           \
      if ((c)&1) { pBu = au; pBv = av; } else { pAu = au; pAv = av; }         \
    }                                                                         \
    if (G1) { /* k1 on u0, row yL-3 */                                        \
      NBR(Uu, Uv, 0, c)                                                       \
      f2 lU, cU, lV, cV;                                                      \
      evalp7(Uu[((c)+2)&7], Uu[((c)+3)&7], Uu[((c)+4)&7], Uu[((c)+5)&7],      \
             Uu[((c)+6)&7], Uu[((c)+7)&7], Uu[(c)&7],                         \
             m1u, p1u, am3u, bp3u, lU, cU);                                   \
      evalp7(Uv[((c)+2)&7], Uv[((c)+3)&7], Uv[((c)+4)&7], Uv[((c)+5)&7],      \
             Uv[((c)+6)&7], Uv[((c)+7)&7], Uv[(c)&7],                         \
             m1v, p1v, am3v, bp3v, lV, cV);                                   \
      f2 uv2 = cU * cV * cV;                                                  \
      f2 kU = pfma(mu_u, lU, pfma(NA, uv2, pfma(-ff, cU, sp(ff))));           \
      f2 kV = pfma(mu_v, lV, pfma(NB, uv2, sp(-kpf) * cV));                   \
      Y1u[(c)&7] = pfma(0.25f, kU, cU);                                       \
      Y1v[(c)&7] = pfma(0.25f, kV, cV);                                       \
      S[1][(c)&3][tid] = cat(Y1u[((c)+7)&7], Y1v[((c)+7)&7]);                 \
    }                                                                         \
    if (G2) { /* k2 on Y1, row yL-6 ; fold AC */                              \
      NBR(Y1u, Y1v, 1, c)                                                     \
      f2 lU, cU, lV, cV;                                                      \
      evalp7(Y1u[((c)+2)&7], Y1u[((c)+3)&7], Y1u[((c)+4)&7], Y1u[((c)+5)&7],  \
             Y1u[((c)+6)&7], Y1u[((c)+7)&7], Y1u[(c)&7],                      \
             m1u, p1u, am3u, bp3u, lU, cU);                                   \
      evalp7(Y1v[((c)+2)&7], Y1v[((c)+3)&7], Y1v[((c)+4)&7], Y1v[((c)+5)&7],  \
             Y1v[((c)+6)&7], Y1v[((c)+7)&7], Y1v[(c)&7],                      \
             m1v, p1v, am3v, bp3v, lV, cV);                                   \
      f2 uv2 = cU * cV * cV;                                                  \
      f2 kU = pfma(mu_u, lU, pfma(NA, uv2, pfma(-ff, cU, sp(ff))));           \
      f2 kV = pfma(mu_v, lV, pfma(NB, uv2, sp(-kpf) * cV));                   \
      f2 bu = Du[((c)+7)&7], bv = Dv[((c)+7)&7];   /* u0 lag 6 */             \
      f2 nu = pfma(0.25f, kU, bu), nv = pfma(0.25f, kV, bv);                  \
      Y2u[(c)&7] = nu; Y2v[(c)&7] = nv;                                       \
      f2 aU = pfma(4.0f, Y1u[((c)+5)&7], sp(8.0f) * nu);                      \
      f2 aV = pfma(4.0f, Y1v[((c)+5)&7], sp(8.0f) * nv);                      \
      ACu[(c)&7] = pfma(-4.0f, bu, aU);                                       \
      ACv[(c)&7] = pfma(-4.0f, bv, aV);                                       \
      S[2][(c)&3][tid] = cat(Y2u[((c)+7)&7], Y2v[((c)+7)&7]);                 \
    }                                                                         \
    if (G3) { /* k3 on Y2, row yL-9 */                                        \
      NBR(Y2u, Y2v, 2, c)                                                     \
      f2 lU, cU, lV, cV;                                                      \
      evalp7(Y2u[((c)+2)&7], Y2u[((c)+3)&7], Y2u[((c)+4)&7], Y2u[((c)+5)&7],  \
             Y2u[((c)+6)&7], Y2u[((c)+7)&7], Y2u[(c)&7],                      \
             m1u, p1u, am3u, bp3u, lU, cU);                                   \
      evalp7(Y2v[((c)+2)&7], Y2v[((c)+3)&7], Y2v[((c)+4)&7], Y2v[((c)+5)&7],  \
             Y2v[((c)+6)&7], Y2v[((c)+7)&7], Y2v[(c)&7],                      \
             m1v, p1v, am3v, bp3v, lV, cV);                                   \
      f2 uv2 = cU * cV * cV;                                                  \
      f2 kU = pfma(mu_u, lU, pfma(NA, uv2, pfma(-ff, cU, sp(ff))));           \
      f2 kV = pfma(mu_v, lV, pfma(NB, uv2, sp(-kpf) * cV));                   \
      Y3u[(c)&7] = pfma(0.5f, kU, Du[((c)+4)&7]);   /* u0 lag 9 */            \
      Y3v[(c)&7] = pfma(0.5f, kV, Dv[((c)+4)&7]);                             \
      S[3][(c)&3][tid] = cat(Y3u[((c)+7)&7], Y3v[((c)+7)&7]);                 \
    }                                                                         \
    if (G4) { /* k4 on Y3, row yL-12 ; write output */                        \
      NBR(Y3u, Y3v, 3, c)                                                     \
      f2 lU, cU4, lV, cV4;                                                    \
      evalp7(Y3u[((c)+2)&7], Y3u[((c)+3)&7], Y3u[((c)+4)&7], Y3u[((c)+5)&7],  \
             Y3u[((c)+6)&7], Y3u[((c)+7)&7], Y3u[(c)&7],                      \
             m1u, p1u, am3u, bp3u, lU, cU4);                                  \
      evalp7(Y3v[((c)+2)&7], Y3v[((c)+3)&7], Y3v[((c)+4)&7], Y3v[((c)+5)&7],  \
             Y3v[((c)+6)&7], Y3v[((c)+7)&7], Y3v[(c)&7],                      \
             m1v, p1v, am3v, bp3v, lV, cV4);                                  \
      f2 uv2 = cU4 * cV4 * cV4;                                               \
      f2 kU = pfma(mu_u, lU, pfma(NA, uv2, pfma(-ff, cU4, sp(ff))));          \
      f2 kV = pfma(mu_v, lV, pfma(NB, uv2, sp(-kpf) * cV4));                  \
      f2 sU = pfma(4.0f, cU4, kU) + ACu[((c)+2)&7];   /* AC lag 6 */          \
      f2 sV = pfma(4.0f, cV4, kV) + ACv[((c)+2)&7];                           \
      f2 oUq = sp(1.0f / 12.0f) * sU;                                         \
      f2 oVq = sp(1.0f / 12.0f) * sV;                                         \
      int yS = Y0 + t_ - 24;                                                  \
      *(f2*)(oU + (size_t)yS * 1024) = oUq;                                   \
      *(f2*)(oV + (size_t)yS * 1024) = oVq;                                   \
    }                                                                         \
    if ((c) & 1) {                                                            \
      asm volatile("s_waitcnt lgkmcnt(0)" ::: "memory");                      \
      __builtin_amdgcn_s_barrier();                                           \
    }                                                                         \
  }

    // warmup: compile-time guards per 8-step block
    STEP(0,0,0,0,0, 0) STEP(1,0,0,0,0, 0) STEP(2,0,0,0,0, 0) STEP(3,0,0,0,0, 0)
    STEP(4,0,0,0,0, 0) STEP(5,0,0,0,0, 0) STEP(6,1,0,0,0, 0) STEP(7,1,0,0,0, 0)

    STEP(0,1,0,0,0, 8) STEP(1,1,0,0,0, 8) STEP(2,1,0,0,0, 8) STEP(3,1,0,0,0, 8)
    STEP(4,1,1,0,0, 8) STEP(5,1,1,0,0, 8) STEP(6,1,1,0,0, 8) STEP(7,1,1,0,0, 8)

    STEP(0,1,1,0,0,16) STEP(1,1,1,0,0,16) STEP(2,1,1,1,0,16) STEP(3,1,1,1,0,16)
    STEP(4,1,1,1,0,16) STEP(5,1,1,1,0,16) STEP(6,1,1,1,0,16) STEP(7,1,1,1,0,16)

    #pragma unroll 1
    for (int tb = 24; tb < STEPS; tb += 8) {
        STEP(0,1,1,1,1,tb) STEP(1,1,1,1,1,tb) STEP(2,1,1,1,1,tb) STEP(3,1,1,1,1,tb)
        STEP(4,1,1,1,1,tb) STEP(5,1,1,1,1,tb) STEP(6,1,1,1,1,tb) STEP(7,1,1,1,1,tb)
    }
#undef STEP
#undef NBR
}

extern "C" void kernel_launch(void* const* d_in, const int* in_sizes, int n_in,
                              void* d_out, int out_size, void* d_ws, size_t ws_size,
                              hipStream_t stream) {
    const float* h   = (const float*)d_in[0];
    const float* pCA = (const float*)d_in[1];
    const float* pCB = (const float*)d_in[2];
    const float* pNA = (const float*)d_in[3];
    const float* pNB = (const float*)d_in[4];
    const float* pf  = (const float*)d_in[5];
    const float* pk  = (const float*)d_in[6];
    float* outp = (float*)d_out;

    dim3 grid(1024 / HROWS, 1, 16);   // 16 strips x 16 batches = 256 blocks
    dim3 block(NT);
    rcnn_rk4_march<<<grid, block, 0, stream>>>(h, pCA, pCB, pNA, pNB, pf, pk, outp);
}